// Round 4
// baseline (291.804 us; speedup 1.0000x reference)
//
#include <hip/hip_runtime.h>

// YOLO-style loss: y_pred (1024,28,28,30) f32, y_true (1024,28,28,5) f32 -> scalar f32.
// DRAM floor: 112.4 MB read @ ~6.3 TB/s ~= 18 us. Harness poison fills (2 x 385 MB ~= 113 us
// at 85% write BW) dominate dur_us and are not controllable from kernel_launch.
// R5 barrier-free wave-private LDS staging: dur 152.0 (best).
// R6 global_load_lds + inline vmcnt(14): 153.3. R7 + opaque-asm ds_reads: 154.2.
// R8 T14 reg-staged async split: 154.4.
//   Post-mortem R6-R8: three structurally distinct pipeline mechanisms are all
//   indistinguishable (+-0.8%) -> the timed window is fixed-cost dominated
//   (2 poison fills ~113us + launch/gap overhead + kernel near its ~18-20us
//   DRAM floor). Pipelining was chasing a phantom; the subtraction-based
//   "~40us kernel" estimate conflated kernel time with dispatch overhead.
// R9 (this): remove the LAST controllable fixed cost -- the second launch.
//   Main loop reverts to the best-measured R5 structure (one-shot, barrier-free
//   wave staging). The 1-block reduce_kernel is replaced by a fence/atomic
//   last-block-done protocol: per-block partial -> __threadfence (release) ->
//   atomicAdd on a counter zeroed by a 4-byte hipMemsetAsync (graph-legal);
//   winner block acquire-fences and reduces 3136 partials in a fixed
//   deterministic order. Saves one dispatch (~6-12us); adds ~2us (tiny fill +
//   winner tail). If dur doesn't move >=3us, window is fill-bound -> ROOFLINE.

#define S_GRID 28
#define N_CELLS (1024 * S_GRID * S_GRID)     // 802816
#define CPW 64                               // cells per wave
#define WPB 4                                // waves per block
#define BLOCK (WPB * 64)                     // 256
#define N_WAVES (N_CELLS / CPW)              // 12544
#define NBLOCKS (N_WAVES / WPB)              // 3136

__device__ __forceinline__ float iou_calc(float bx, float by, float bw, float bh,
                                          float tx, float ty, float tw, float th,
                                          float gi, float gj) {
    float acx = (gj + bx) * 8.0f;
    float acy = (gi + by) * 8.0f;
    float aw  = bw * 224.0f;
    float ah  = bh * 224.0f;
    float ax1 = acx - aw * 0.5f, ax2 = acx + aw * 0.5f;
    float ay1 = acy - ah * 0.5f, ay2 = acy + ah * 0.5f;
    float bcx = (gj + tx) * 8.0f;
    float bcy = (gi + ty) * 8.0f;
    float btw = tw * 224.0f;
    float bth = th * 224.0f;
    float bx1 = bcx - btw * 0.5f, bx2 = bcx + btw * 0.5f;
    float by1 = bcy - bth * 0.5f, by2 = bcy + bth * 0.5f;

    float iw = fmaxf(fminf(ax2, bx2) - fmaxf(ax1, bx1), 0.0f);
    float ih = fmaxf(fminf(ay2, by2) - fmaxf(ay1, by1), 0.0f);
    float inter = iw * ih;
    float area_a = fmaxf(ax2 - ax1, 0.0f) * fmaxf(ay2 - ay1, 0.0f);
    float area_b = fmaxf(bx2 - bx1, 0.0f) * fmaxf(by2 - by1, 0.0f);
    return inter / (area_a + area_b - inter + 1e-12f);
}

// workspace layout: [0..3] counter (memset to 0 each call), [256..] block partials
__global__ __launch_bounds__(BLOCK, 4) void yolo_loss_kernel(const float2* __restrict__ yp2,
                                                             const float* __restrict__ yt,
                                                             unsigned int* __restrict__ counter,
                                                             float* __restrict__ partials,
                                                             float* __restrict__ out) {
    // wave-private pred slabs, raw (global) layout: 64 cells x 30 floats = 7680 B each
    __shared__ float sp[WPB][CPW * 30];
    __shared__ float wsum[WPB];

    int tid  = threadIdx.x;
    int lane = tid & 63;
    int wave = tid >> 6;
    int gwave = blockIdx.x * WPB + wave;     // global wave id = tile id

    // ---- stage y_pred tile: 960 float2; 15 float2/lane, lane-major, coalesced ----
    const float2* pb = yp2 + (size_t)gwave * (CPW * 30 / 2);
    float2 v[15];
#pragma unroll
    for (int k = 0; k < 15; ++k) v[k] = pb[k * 64 + lane];

    float2* spw2 = (float2*)sp[wave];
#pragma unroll
    for (int k = 0; k < 15; ++k) spw2[k * 64 + lane] = v[k];

    // ---- y_true: own cell's 5 floats; direct loads, L1 serves line reuse ----
    int cell = gwave * CPW + lane;
    const float* t = yt + (size_t)cell * 5;
    float tc = t[0], tx = t[1], ty = t[2], tw = t[3], th = t[4];

    // ---- read back own cell's 30 channels (stride 30: 4 lanes/bank, ~free) ----
    float pr[30];
    const float* p = sp[wave] + lane * 30;
#pragma unroll
    for (int k = 0; k < 30; ++k) pr[k] = p[k];

    // ---- per-cell loss, branch-free select ----
    int ij = cell % (S_GRID * S_GRID);
    float gi = (float)(ij / S_GRID);
    float gj = (float)(ij % S_GRID);

    float iou0 = iou_calc(pr[0], pr[1], pr[2], pr[3], tx, ty, tw, th, gi, gj);
    float iou1 = iou_calc(pr[5], pr[6], pr[7], pr[8], tx, ty, tw, th, gi, gj);
    bool choose1 = !(iou0 > iou1);

    float conf_pred = choose1 ? pr[9] : pr[4];
    float conf_true = choose1 ? iou1 : iou0;
    float xp = choose1 ? pr[5] : pr[0];
    float yp = choose1 ? pr[6] : pr[1];

    float dcf = conf_pred - conf_true;
    float d0 = xp - tx, d1 = yp - ty;

    int cls = (int)tc - 1;   // -1 => one-hot all zeros
    float lcls = 0.0f;
#pragma unroll
    for (int k = 0; k < 20; ++k) {
        float oh = (k == cls) ? 1.0f : 0.0f;
        float d = pr[10 + k] - oh;
        lcls += d * d;
    }

    float obj_loss   = dcf * dcf + 5.0f * (d0 * d0 + d1 * d1) + lcls;
    float noobj_loss = 0.5f * (pr[4] * pr[4] + pr[9] * pr[9]);
    float val = (tc != 0.0f) ? obj_loss : noobj_loss;

    // ---- wave-local reduction ----
#pragma unroll
    for (int off = 32; off > 0; off >>= 1) {
        val += __shfl_down(val, off, 64);
    }
    if (lane == 0) wsum[wave] = val;
    __syncthreads();   // single end-of-block barrier (cheap: all compute done)

    // ---- block partial + last-block-done protocol ----
    if (wave == 0) {
        unsigned int old = 0u;
        if (lane == 0) {
            float bsum = (wsum[0] + wsum[1]) + (wsum[2] + wsum[3]);
            partials[blockIdx.x] = bsum;
            __threadfence();                       // release: partial visible device-wide
            old = atomicAdd(counter, 1u) + 1u;     // device-scope by default
        }
        old = __shfl(old, 0, 64);                  // broadcast winner status to wave0
        if (old == NBLOCKS) {
            __threadfence();                       // acquire: see all partials
            float s = 0.0f;
#pragma unroll
            for (int k = 0; k < 49; ++k) {         // 49 * 64 = 3136 exact, fixed order
                s += partials[k * 64 + lane];
            }
#pragma unroll
            for (int off = 32; off > 0; off >>= 1) {
                s += __shfl_down(s, off, 64);
            }
            if (lane == 0) out[0] = s * (1.0f / 1024.0f);
        }
    }
}

extern "C" void kernel_launch(void* const* d_in, const int* in_sizes, int n_in,
                              void* d_out, int out_size, void* d_ws, size_t ws_size,
                              hipStream_t stream) {
    const float2* y_pred = (const float2*)d_in[0];
    const float*  y_true = (const float*)d_in[1];
    float* out = (float*)d_out;
    unsigned int* counter = (unsigned int*)d_ws;           // 4 B, zeroed below
    float* partials = (float*)((char*)d_ws + 256);         // 3136 floats, own cache lines

    hipMemsetAsync(d_ws, 0, 4, stream);                    // graph-capture-legal
    yolo_loss_kernel<<<NBLOCKS, BLOCK, 0, stream>>>(y_pred, y_true, counter, partials, out);
}

// Round 5
// 163.951 us; speedup vs baseline: 1.7798x; 1.7798x over previous
//
#include <hip/hip_runtime.h>

// YOLO-style loss: y_pred (1024,28,28,30) f32, y_true (1024,28,28,5) f32 -> scalar f32.
// Window anatomy (measured): 2 harness poison fills ~113us (uncontrollable) + main
// kernel ~30us (FETCH 54.9 MB, L3 absorbs rest of 112 MB) + reduce launch + gaps.
// R5 barrier-free wave-private LDS staging + separate reduce kernel: dur 152.0 (best).
// R6-R8 three distinct software pipelines: 153.3/154.2/154.4 -> kernel is not
//   latency-structure-bound; window is fixed-cost dominated.
// R9 fence/atomic last-block protocol: dur 291.8. Kernel exposed at 181us,
//   VALUBusy 2.9%: per-block __threadfence at agent scope = L2 writeback/inv on
//   non-coherent per-XCD L2s, serialized across 3136 blocks ~ +140us. Fences are
//   catastrophic here; the atomics themselves are cheap.
// R10 (this): merge launches FENCE-FREE. Cross-block data uses agent-scope RELAXED
//   atomic store/load (sc1 coherent ops that bypass stale per-XCD L2 -- no
//   buffer_wbl2/inv emitted for relaxed). Block order: coherent-store partial ->
//   s_waitcnt vmcnt(0) (store acked at coherence point) -> relaxed atomicAdd
//   counter. Winner (old+1==NBLOCKS) sums 3136 partials via coherent loads in the
//   SAME fixed tree as the old reduce_kernel -> bitwise-identical (absmax 0).
//   Saves one dispatch + gap vs R5; adds a 4-byte memset dispatch.

#define S_GRID 28
#define N_CELLS (1024 * S_GRID * S_GRID)     // 802816
#define CPW 64                               // cells per wave
#define WPB 4                                // waves per block
#define BLOCK (WPB * 64)                     // 256
#define N_WAVES (N_CELLS / CPW)              // 12544
#define NBLOCKS (N_WAVES / WPB)              // 3136

__device__ __forceinline__ float iou_calc(float bx, float by, float bw, float bh,
                                          float tx, float ty, float tw, float th,
                                          float gi, float gj) {
    float acx = (gj + bx) * 8.0f;
    float acy = (gi + by) * 8.0f;
    float aw  = bw * 224.0f;
    float ah  = bh * 224.0f;
    float ax1 = acx - aw * 0.5f, ax2 = acx + aw * 0.5f;
    float ay1 = acy - ah * 0.5f, ay2 = acy + ah * 0.5f;
    float bcx = (gj + tx) * 8.0f;
    float bcy = (gi + ty) * 8.0f;
    float btw = tw * 224.0f;
    float bth = th * 224.0f;
    float bx1 = bcx - btw * 0.5f, bx2 = bcx + btw * 0.5f;
    float by1 = bcy - bth * 0.5f, by2 = bcy + bth * 0.5f;

    float iw = fmaxf(fminf(ax2, bx2) - fmaxf(ax1, bx1), 0.0f);
    float ih = fmaxf(fminf(ay2, by2) - fmaxf(ay1, by1), 0.0f);
    float inter = iw * ih;
    float area_a = fmaxf(ax2 - ax1, 0.0f) * fmaxf(ay2 - ay1, 0.0f);
    float area_b = fmaxf(bx2 - bx1, 0.0f) * fmaxf(by2 - by1, 0.0f);
    return inter / (area_a + area_b - inter + 1e-12f);
}

// workspace layout: [0..3] counter (memset to 0 each call), [256..] block partials
__global__ __launch_bounds__(BLOCK, 4) void yolo_loss_kernel(const float2* __restrict__ yp2,
                                                             const float* __restrict__ yt,
                                                             unsigned int* __restrict__ counter,
                                                             float* __restrict__ partials,
                                                             float* __restrict__ out) {
    // wave-private pred slabs, raw (global) layout: 64 cells x 30 floats = 7680 B each
    __shared__ float sp[WPB][CPW * 30];
    __shared__ float wsum[WPB];

    int tid  = threadIdx.x;
    int lane = tid & 63;
    int wave = tid >> 6;
    int gwave = blockIdx.x * WPB + wave;     // global wave id = tile id

    // ---- stage y_pred tile: 960 float2; 15 float2/lane, lane-major, coalesced ----
    const float2* pb = yp2 + (size_t)gwave * (CPW * 30 / 2);
    float2 v[15];
#pragma unroll
    for (int k = 0; k < 15; ++k) v[k] = pb[k * 64 + lane];

    float2* spw2 = (float2*)sp[wave];
#pragma unroll
    for (int k = 0; k < 15; ++k) spw2[k * 64 + lane] = v[k];

    // ---- y_true: own cell's 5 floats; direct loads, L1 serves line reuse ----
    int cell = gwave * CPW + lane;
    const float* t = yt + (size_t)cell * 5;
    float tc = t[0], tx = t[1], ty = t[2], tw = t[3], th = t[4];

    // ---- read back own cell's 30 channels (stride 30: 4 lanes/bank, ~free) ----
    float pr[30];
    const float* p = sp[wave] + lane * 30;
#pragma unroll
    for (int k = 0; k < 30; ++k) pr[k] = p[k];

    // ---- per-cell loss, branch-free select ----
    int ij = cell % (S_GRID * S_GRID);
    float gi = (float)(ij / S_GRID);
    float gj = (float)(ij % S_GRID);

    float iou0 = iou_calc(pr[0], pr[1], pr[2], pr[3], tx, ty, tw, th, gi, gj);
    float iou1 = iou_calc(pr[5], pr[6], pr[7], pr[8], tx, ty, tw, th, gi, gj);
    bool choose1 = !(iou0 > iou1);

    float conf_pred = choose1 ? pr[9] : pr[4];
    float conf_true = choose1 ? iou1 : iou0;
    float xp = choose1 ? pr[5] : pr[0];
    float yp = choose1 ? pr[6] : pr[1];

    float dcf = conf_pred - conf_true;
    float d0 = xp - tx, d1 = yp - ty;

    int cls = (int)tc - 1;   // -1 => one-hot all zeros
    float lcls = 0.0f;
#pragma unroll
    for (int k = 0; k < 20; ++k) {
        float oh = (k == cls) ? 1.0f : 0.0f;
        float d = pr[10 + k] - oh;
        lcls += d * d;
    }

    float obj_loss   = dcf * dcf + 5.0f * (d0 * d0 + d1 * d1) + lcls;
    float noobj_loss = 0.5f * (pr[4] * pr[4] + pr[9] * pr[9]);
    float val = (tc != 0.0f) ? obj_loss : noobj_loss;

    // ---- wave-local reduction ----
#pragma unroll
    for (int off = 32; off > 0; off >>= 1) {
        val += __shfl_down(val, off, 64);
    }
    if (lane == 0) wsum[wave] = val;
    __syncthreads();   // single end-of-block barrier (all compute done, cheap)

    // ---- merged reduction: coherent accesses, NO fences (no L2 wb/inv) ----
    if (wave == 0) {
        unsigned int old = 0u;
        if (lane == 0) {
            float bsum = (wsum[0] + wsum[1]) + (wsum[2] + wsum[3]);
            // coherent (sc1) store: visible device-wide once acked
            __hip_atomic_store(&partials[blockIdx.x], bsum,
                               __ATOMIC_RELAXED, __HIP_MEMORY_SCOPE_AGENT);
            // order store -> counter RMW: wait for store ack at coherence point
            asm volatile("s_waitcnt vmcnt(0)" ::);
            old = __hip_atomic_fetch_add(counter, 1u,
                                         __ATOMIC_RELAXED, __HIP_MEMORY_SCOPE_AGENT) + 1u;
        }
        old = __shfl(old, 0, 64);                  // broadcast winner status
        if (old == NBLOCKS) {
            // winner: sum all partials with coherent loads (bypass stale L2),
            // fixed deterministic tree identical to the old reduce_kernel
            float s = 0.0f;
#pragma unroll 7
            for (int k = 0; k < 49; ++k) {         // 49 * 64 = 3136 exact
                s += __hip_atomic_load(&partials[k * 64 + lane],
                                       __ATOMIC_RELAXED, __HIP_MEMORY_SCOPE_AGENT);
            }
#pragma unroll
            for (int off = 32; off > 0; off >>= 1) {
                s += __shfl_down(s, off, 64);
            }
            if (lane == 0) out[0] = s * (1.0f / 1024.0f);
        }
    }
}

extern "C" void kernel_launch(void* const* d_in, const int* in_sizes, int n_in,
                              void* d_out, int out_size, void* d_ws, size_t ws_size,
                              hipStream_t stream) {
    const float2* y_pred = (const float2*)d_in[0];
    const float*  y_true = (const float*)d_in[1];
    float* out = (float*)d_out;
    unsigned int* counter = (unsigned int*)d_ws;           // 4 B, zeroed below
    float* partials = (float*)((char*)d_ws + 256);         // 3136 floats

    hipMemsetAsync(d_ws, 0, 4, stream);                    // graph-capture-legal
    yolo_loss_kernel<<<NBLOCKS, BLOCK, 0, stream>>>(y_pred, y_true, counter, partials, out);
}

// Round 6
// 153.002 us; speedup vs baseline: 1.9072x; 1.0716x over previous
//
#include <hip/hip_runtime.h>

// YOLO-style loss: y_pred (1024,28,28,30) f32, y_true (1024,28,28,5) f32 -> scalar f32.
// FINAL (R11) = R5 restored verbatim: best-measured structure, dur 152.0.
// Window anatomy (measured over R5-R10): 2 harness poison fills ~113us at 85% of
// peak write BW (uncontrollable) + main kernel ~25-30us + reduce dispatch + gaps.
// Exhausted mechanisms, all measured:
//   R6 global_load_lds + counted vmcnt(14):   153.3 (null -- waitcnt pass drains)
//   R7 + opaque-asm ds_reads:                 154.2 (null -- same)
//   R8 T14 reg-staged async split:            154.4 (null -- already BW-saturated:
//       one-shot in-flight ~122 KB/CU >> ~17 KB Little's-law need at 6.3 TB/s)
//   R9 merged epilogue via __threadfence:     291.8 (agent fence = per-block L2
//       writeback/inv on non-coherent XCD L2s -- catastrophic)
//   R10 merged epilogue via sc1 coherent ops: 164.0 (uncached winner reduction +
//       per-block store-ack round-trips cost more than the reduce dispatch)
// Conclusion: two-launch R5 structure is the empirical optimum; remaining time is
// harness fills + a main kernel within ~2x of its L3/HBM service floor whose
// latency structure is already hidden by occupancy (16 waves/CU).

#define S_GRID 28
#define N_CELLS (1024 * S_GRID * S_GRID)     // 802816
#define CPW 64                               // cells per wave
#define WPB 4                                // waves per block
#define BLOCK (WPB * 64)                     // 256
#define N_WAVES (N_CELLS / CPW)              // 12544
#define NBLOCKS (N_WAVES / WPB)              // 3136

__device__ __forceinline__ float iou_calc(float bx, float by, float bw, float bh,
                                          float tx, float ty, float tw, float th,
                                          float gi, float gj) {
    float acx = (gj + bx) * 8.0f;
    float acy = (gi + by) * 8.0f;
    float aw  = bw * 224.0f;
    float ah  = bh * 224.0f;
    float ax1 = acx - aw * 0.5f, ax2 = acx + aw * 0.5f;
    float ay1 = acy - ah * 0.5f, ay2 = acy + ah * 0.5f;
    float bcx = (gj + tx) * 8.0f;
    float bcy = (gi + ty) * 8.0f;
    float btw = tw * 224.0f;
    float bth = th * 224.0f;
    float bx1 = bcx - btw * 0.5f, bx2 = bcx + btw * 0.5f;
    float by1 = bcy - bth * 0.5f, by2 = bcy + bth * 0.5f;

    float iw = fmaxf(fminf(ax2, bx2) - fmaxf(ax1, bx1), 0.0f);
    float ih = fmaxf(fminf(ay2, by2) - fmaxf(ay1, by1), 0.0f);
    float inter = iw * ih;
    float area_a = fmaxf(ax2 - ax1, 0.0f) * fmaxf(ay2 - ay1, 0.0f);
    float area_b = fmaxf(bx2 - bx1, 0.0f) * fmaxf(by2 - by1, 0.0f);
    return inter / (area_a + area_b - inter + 1e-12f);
}

__global__ __launch_bounds__(BLOCK, 4) void yolo_loss_kernel(const float2* __restrict__ yp2,
                                                             const float* __restrict__ yt,
                                                             float* __restrict__ partials) {
    // wave-private pred slabs, raw (global) layout: 64 cells x 30 floats = 7680 B each
    __shared__ float sp[WPB][CPW * 30];

    int tid  = threadIdx.x;
    int lane = tid & 63;
    int wave = tid >> 6;
    int gwave = blockIdx.x * WPB + wave;     // global wave id = tile id

    // ---- stage y_pred tile: 1920 floats = 960 float2; 15 float2/lane, lane-major
    // each wave instruction covers 512 B contiguous -> fully coalesced ----
    const float2* pb = yp2 + (size_t)gwave * (CPW * 30 / 2);   // 960 float2 per wave
    float2 v[15];
#pragma unroll
    for (int k = 0; k < 15; ++k) v[k] = pb[k * 64 + lane];

    // raw layout: float2 index == LDS float2 index -> lane-contiguous, conflict-free
    float2* spw2 = (float2*)sp[wave];
#pragma unroll
    for (int k = 0; k < 15; ++k) spw2[k * 64 + lane] = v[k];

    // ---- y_true: each lane needs only its own cell's 5 floats; direct loads,
    // L1 serves the repeated line touches (no cross-lane use -> no staging) ----
    int cell = gwave * CPW + lane;
    const float* t = yt + (size_t)cell * 5;
    float tc = t[0], tx = t[1], ty = t[2], tw = t[3], th = t[4];

    // ---- read back own cell's 30 channels (stride 30: 4 lanes/bank, ~free) ----
    float pr[30];
    const float* p = sp[wave] + lane * 30;
#pragma unroll
    for (int k = 0; k < 30; ++k) pr[k] = p[k];

    // ---- per-cell loss, branch-free select ----
    int ij = cell % (S_GRID * S_GRID);
    float gi = (float)(ij / S_GRID);
    float gj = (float)(ij % S_GRID);

    float iou0 = iou_calc(pr[0], pr[1], pr[2], pr[3], tx, ty, tw, th, gi, gj);
    float iou1 = iou_calc(pr[5], pr[6], pr[7], pr[8], tx, ty, tw, th, gi, gj);
    bool choose1 = !(iou0 > iou1);

    float conf_pred = choose1 ? pr[9] : pr[4];
    float conf_true = choose1 ? iou1 : iou0;
    float xp = choose1 ? pr[5] : pr[0];
    float yp = choose1 ? pr[6] : pr[1];

    float dcf = conf_pred - conf_true;
    float d0 = xp - tx, d1 = yp - ty;

    int cls = (int)tc - 1;   // -1 => one-hot all zeros
    float lcls = 0.0f;
#pragma unroll
    for (int k = 0; k < 20; ++k) {
        float oh = (k == cls) ? 1.0f : 0.0f;
        float d = pr[10 + k] - oh;
        lcls += d * d;
    }

    float obj_loss   = dcf * dcf + 5.0f * (d0 * d0 + d1 * d1) + lcls;
    float noobj_loss = 0.5f * (pr[4] * pr[4] + pr[9] * pr[9]);
    float val = (tc != 0.0f) ? obj_loss : noobj_loss;

    // ---- wave-local reduction only; one partial per wave, NO barrier ----
#pragma unroll
    for (int off = 32; off > 0; off >>= 1) {
        val += __shfl_down(val, off, 64);
    }
    if (lane == 0) partials[gwave] = val;
}

__global__ __launch_bounds__(256) void reduce_kernel(const float* __restrict__ partials,
                                                     float* __restrict__ out) {
    int tid = threadIdx.x;
    float s = 0.0f;
#pragma unroll
    for (int k = 0; k < 49; ++k) {          // 49 * 256 = 12544 exact
        s += partials[k * 256 + tid];
    }
#pragma unroll
    for (int off = 32; off > 0; off >>= 1) {
        s += __shfl_down(s, off, 64);
    }
    __shared__ float wsum[4];
    int lane = tid & 63;
    int wid  = tid >> 6;
    if (lane == 0) wsum[wid] = s;
    __syncthreads();
    if (tid == 0) {
        out[0] = (wsum[0] + wsum[1] + wsum[2] + wsum[3]) * (1.0f / 1024.0f);
    }
}

extern "C" void kernel_launch(void* const* d_in, const int* in_sizes, int n_in,
                              void* d_out, int out_size, void* d_ws, size_t ws_size,
                              hipStream_t stream) {
    const float2* y_pred = (const float2*)d_in[0];
    const float*  y_true = (const float*)d_in[1];
    float* out = (float*)d_out;
    float* partials = (float*)d_ws;   // 12544 floats, fully overwritten each call

    yolo_loss_kernel<<<NBLOCKS, BLOCK, 0, stream>>>(y_pred, y_true, partials);
    reduce_kernel<<<1, 256, 0, stream>>>(partials, out);
}